// Round 1
// baseline (724.467 us; speedup 1.0000x reference)
//
#include <hip/hip_runtime.h>
#include <math.h>

#define BB 4
#define CC 64
#define HH 128
#define WW 128
#define HWP (HH*WW)   // 16384

// ---------------- K1: 3x3 conv over concat[f1,f3] (128ch) -> om [B][27][H][W], pad=1
__global__ __launch_bounds__(256) void k1_offset_conv(
    const float* __restrict__ f1, const float* __restrict__ f3,
    const float* __restrict__ ow, const float* __restrict__ ob,
    float* __restrict__ om)
{
    extern __shared__ float wl[];  // [27*128 rows][10] (9 taps + 1 pad)
    for (int e = threadIdx.x; e < 27*128*9; e += 256) {
        int r = e / 9;
        int t = e - r*9;
        wl[r*10 + t] = ow[e];
    }
    __syncthreads();

    int pix = blockIdx.x*256 + threadIdx.x;
    int b = pix >> 14;
    int y = (pix >> 7) & 127;
    int x = pix & 127;

    int   toff[9];
    float tval[9];
#pragma unroll
    for (int t = 0; t < 9; ++t) {
        int yy = y + t/3 - 1;
        int xx = x + (t % 3) - 1;
        bool ok = ((unsigned)yy < (unsigned)HH) && ((unsigned)xx < (unsigned)WW);
        tval[t] = ok ? 1.f : 0.f;
        toff[t] = ok ? (yy*WW + xx) : 0;
    }

    float acc[27];
#pragma unroll
    for (int k = 0; k < 27; ++k) acc[k] = ob[k];

    const float* base0 = f1 + ((size_t)(b*CC) << 14);
    const float* base1 = f3 + ((size_t)(b*CC) << 14);

    for (int half = 0; half < 2; ++half) {
        const float* srcb = (half == 0) ? base0 : base1;
        for (int c0 = 0; c0 < 64; ++c0) {
            const float* src = srcb + (c0 << 14);
            int c = half*64 + c0;
            float v[9];
#pragma unroll
            for (int t = 0; t < 9; ++t) v[t] = tval[t] * src[toff[t]];
#pragma unroll
            for (int k = 0; k < 27; ++k) {
                const float* wr = &wl[(k*128 + c)*10];
#pragma unroll
                for (int t = 0; t < 9; ++t) acc[k] += v[t]*wr[t];
            }
        }
    }

    int obase = ((b*27) << 14) + (y << 7) + x;
#pragma unroll
    for (int k = 0; k < 27; ++k)
        om[obase + (k << 14)] = acc[k];
}

// ---------------- K2: deformable conv; writes aligned into d_out
// block = one row (b,y); 4 chunks of 16 input channels.
// phase A: lane=pixel bilinear sampling -> sl[ck][128]
// phase B: 8x4 register tile micro-GEMM, lane -> (oo = tid&7, pg = tid>>3)
__global__ __launch_bounds__(256) void k2_deform(
    const float* __restrict__ f1, const float* __restrict__ mw,
    const float* __restrict__ om, float* __restrict__ aligned)
{
    extern __shared__ float lds[];
    float* sl = lds;              // [144][128]
    float* wl = lds + 144*128;    // [64][148] (ck stride padded to 148)

    int row = blockIdx.x;         // 0..511
    int b = row >> 7;
    int y = row & 127;

    int tid  = threadIdx.x;
    int px   = tid & 127;
    int half = tid >> 7;
    int oo   = tid & 7;
    int pg   = tid >> 3;          // 0..31

    float acc[8][4];
#pragma unroll
    for (int j = 0; j < 8; ++j)
#pragma unroll
        for (int p = 0; p < 4; ++p) acc[j][p] = 0.f;

    const float* omb = om + ((b*27) << 14) + (y << 7);
    const float* f1b = f1 + ((size_t)(b*CC) << 14);

    for (int chunk = 0; chunk < 4; ++chunk) {
        // stage weights: wl[o][ck] = mw[o*576 + chunk*144 + ck], float4 at a time
        for (int q = tid; q < 64*36; q += 256) {
            int o = q / 36;
            int ck4 = (q - o*36) * 4;
            float4 wv = *(const float4*)&mw[o*576 + chunk*144 + ck4];
            *(float4*)&wl[o*148 + ck4] = wv;
        }

        // phase A: sampling. this thread: c_local = half*8 + cl (cl 0..7), pixel px
        for (int k = 0; k < 9; ++k) {
            float off0 = omb[((2*k)   << 14) + px];
            float off1 = omb[((2*k+1) << 14) + px];
            float mk   = omb[((18+k)  << 14) + px];
            mk = 1.f / (1.f + __expf(-mk));

            float pyf = (float)y  + (float)(k/3) - 1.f + off0;
            float pxg = (float)px + (float)(k%3) - 1.f + off1;
            float fy = floorf(pyf), fx = floorf(pxg);
            int y0 = (int)fy, x0 = (int)fx;
            float wy = pyf - fy, wx = pxg - fx;
            float oy = 1.f - wy, ox = 1.f - wx;
            float w00 = oy*ox, w01 = oy*wx, w10 = wy*ox, w11 = wy*wx;
            bool yv0 = (unsigned)y0     < (unsigned)HH;
            bool yv1 = (unsigned)(y0+1) < (unsigned)HH;
            bool xv0 = (unsigned)x0     < (unsigned)WW;
            bool xv1 = (unsigned)(x0+1) < (unsigned)WW;
            int i00 = y0*WW + x0;

#pragma unroll
            for (int cl = 0; cl < 8; ++cl) {
                int c = chunk*16 + half*8 + cl;
                const float* src = f1b + (c << 14);
                float s = 0.f;
                if (yv0 && xv0) s += w00 * src[i00];
                if (yv0 && xv1) s += w01 * src[i00 + 1];
                if (yv1 && xv0) s += w10 * src[i00 + WW];
                if (yv1 && xv1) s += w11 * src[i00 + WW + 1];
                s *= mk;
                sl[((half*8 + cl)*9 + k)*128 + px] = s;
            }
        }
        __syncthreads();

        // phase B: acc[j][p] += w[oo+8j][ck+q] * s[ck+q][pg*4+p]
        for (int ck = 0; ck < 144; ck += 4) {
            float4 s0 = *(const float4*)&sl[(ck+0)*128 + pg*4];
            float4 s1 = *(const float4*)&sl[(ck+1)*128 + pg*4];
            float4 s2 = *(const float4*)&sl[(ck+2)*128 + pg*4];
            float4 s3 = *(const float4*)&sl[(ck+3)*128 + pg*4];
#pragma unroll
            for (int j = 0; j < 8; ++j) {
                float4 wv = *(const float4*)&wl[(oo + 8*j)*148 + ck];
                acc[j][0] += wv.x*s0.x + wv.y*s1.x + wv.z*s2.x + wv.w*s3.x;
                acc[j][1] += wv.x*s0.y + wv.y*s1.y + wv.z*s2.y + wv.w*s3.y;
                acc[j][2] += wv.x*s0.z + wv.y*s1.z + wv.z*s2.z + wv.w*s3.z;
                acc[j][3] += wv.x*s0.w + wv.y*s1.w + wv.z*s2.w + wv.w*s3.w;
            }
        }
        __syncthreads();
    }

#pragma unroll
    for (int j = 0; j < 8; ++j) {
        int o = oo + 8*j;
        float4 v = make_float4(acc[j][0], acc[j][1], acc[j][2], acc[j][3]);
        *(float4*)&aligned[((b*CC + o) << 14) + (y << 7) + pg*4] = v;
    }
}

// ---------------- K3: per-channel sum / sumsq over (B,H,W); one block per channel
__global__ __launch_bounds__(256) void k3_stats(
    const float* __restrict__ a, float* __restrict__ stats)
{
    int c = blockIdx.x;
    int tid = threadIdx.x;
    float s = 0.f, s2 = 0.f;
    for (int bimg = 0; bimg < BB; ++bimg) {
        const float* base = a + ((size_t)(bimg*CC + c) << 14);
        for (int i = tid*4; i < HWP; i += 256*4) {
            float4 v = *(const float4*)&base[i];
            s  += v.x + v.y + v.z + v.w;
            s2 += v.x*v.x + v.y*v.y + v.z*v.z + v.w*v.w;
        }
    }
    for (int off = 32; off > 0; off >>= 1) {
        s  += __shfl_down(s,  off, 64);
        s2 += __shfl_down(s2, off, 64);
    }
    __shared__ float rs[4], rs2[4];
    int w = tid >> 6;
    if ((tid & 63) == 0) { rs[w] = s; rs2[w] = s2; }
    __syncthreads();
    if (tid == 0) {
        stats[c]      = rs[0] + rs[1] + rs[2] + rs[3];
        stats[64 + c] = rs2[0] + rs2[1] + rs2[2] + rs2[3];
    }
}

// ---------------- K4: in-place normalize + affine
__global__ __launch_bounds__(256) void k4_norm(
    float* __restrict__ a, const float* __restrict__ stats,
    const float* __restrict__ gamma, const float* __restrict__ beta)
{
    const float invN = 1.f / 65536.f;
    int n4 = (BB*CC*HWP) / 4;
    for (int i4 = blockIdx.x*256 + threadIdx.x; i4 < n4; i4 += gridDim.x*256) {
        int c = (i4 >> 12) & 63;
        float mean = stats[c] * invN;
        float var  = stats[64 + c] * invN - mean*mean;
        float sc = gamma[c] * rsqrtf(var + 1e-5f);
        float sh = beta[c] - mean*sc;
        float4 v = ((const float4*)a)[i4];
        v.x = v.x*sc + sh; v.y = v.y*sc + sh;
        v.z = v.z*sc + sh; v.w = v.w*sc + sh;
        ((float4*)a)[i4] = v;
    }
}

extern "C" void kernel_launch(void* const* d_in, const int* in_sizes, int n_in,
                              void* d_out, int out_size, void* d_ws, size_t ws_size,
                              hipStream_t stream)
{
    const float* f1    = (const float*)d_in[0];
    const float* f3    = (const float*)d_in[1];
    const float* ow    = (const float*)d_in[2];
    const float* ob    = (const float*)d_in[3];
    const float* mw    = (const float*)d_in[4];
    const float* gamma = (const float*)d_in[5];
    const float* beta  = (const float*)d_in[6];
    float* out = (float*)d_out;

    float* om    = (float*)d_ws;               // [4][27][128][128] = 7,077,888 B
    float* stats = om + 4*27*HWP;              // [128] floats

    const int lds1 = 27*128*10*4;              // 138,240 B
    const int lds2 = (144*128 + 64*148)*4;     // 111,616 B
    (void)hipFuncSetAttribute((const void*)k1_offset_conv,
        hipFuncAttributeMaxDynamicSharedMemorySize, lds1);
    (void)hipFuncSetAttribute((const void*)k2_deform,
        hipFuncAttributeMaxDynamicSharedMemorySize, lds2);

    hipLaunchKernelGGL(k1_offset_conv, dim3(256), dim3(256), lds1, stream,
                       f1, f3, ow, ob, om);
    hipLaunchKernelGGL(k2_deform, dim3(512), dim3(256), lds2, stream,
                       f1, mw, om, out);
    hipLaunchKernelGGL(k3_stats, dim3(64), dim3(256), 0, stream, out, stats);
    hipLaunchKernelGGL(k4_norm, dim3(1024), dim3(256), 0, stream,
                       out, stats, gamma, beta);
}

// Round 2
// 643.159 us; speedup vs baseline: 1.1264x; 1.1264x over previous
//
#include <hip/hip_runtime.h>
#include <math.h>

#define BB 4
#define CC 64
#define HH 128
#define WW 128
#define HWP 16384

// ---------------- K1: 3x3 conv over concat[f1,f3] (128ch) -> om [B][27][H][W]
// grid (256 pixel-blocks, 3 output-groups); each block does 9 of 27 outputs.
// Group 2 (channels 18..26) gets sigmoid applied (mask), so K2 skips expf.
__global__ __launch_bounds__(256) void k1_offset_conv(
    const float* __restrict__ f1, const float* __restrict__ f3,
    const float* __restrict__ ow, const float* __restrict__ ob,
    float* __restrict__ om)
{
    extern __shared__ float wl[];  // [9*128 rows][10] (9 taps + 1 pad) = 46080 B
    int grp = blockIdx.y;          // 0..2
    for (int e = threadIdx.x; e < 9*128*9; e += 256) {
        int r = e / 9;
        int t = e - r*9;
        wl[r*10 + t] = ow[grp*(9*128*9) + e];
    }
    __syncthreads();

    int pix = blockIdx.x*256 + threadIdx.x;
    int b = pix >> 14;
    int y = (pix >> 7) & 127;
    int x = pix & 127;

    int   toff[9];
    float tval[9];
#pragma unroll
    for (int t = 0; t < 9; ++t) {
        int yy = y + t/3 - 1;
        int xx = x + (t % 3) - 1;
        bool ok = ((unsigned)yy < (unsigned)HH) && ((unsigned)xx < (unsigned)WW);
        tval[t] = ok ? 1.f : 0.f;
        toff[t] = ok ? (yy*WW + xx) : 0;
    }

    float acc[9];
#pragma unroll
    for (int k = 0; k < 9; ++k) acc[k] = ob[grp*9 + k];

    const float* base0 = f1 + ((size_t)(b*CC) << 14);
    const float* base1 = f3 + ((size_t)(b*CC) << 14);

    for (int half = 0; half < 2; ++half) {
        const float* srcb = (half == 0) ? base0 : base1;
        for (int c0 = 0; c0 < 64; ++c0) {
            const float* src = srcb + (c0 << 14);
            int c = half*64 + c0;
            float v[9];
#pragma unroll
            for (int t = 0; t < 9; ++t) v[t] = tval[t] * src[toff[t]];
#pragma unroll
            for (int k = 0; k < 9; ++k) {
                const float* wr = &wl[(k*128 + c)*10];
#pragma unroll
                for (int t = 0; t < 9; ++t) acc[k] += v[t]*wr[t];
            }
        }
    }

    int obase = ((b*27 + grp*9) << 14) + (y << 7) + x;
#pragma unroll
    for (int k = 0; k < 9; ++k) {
        float a = acc[k];
        if (grp == 2) a = 1.f / (1.f + __expf(-a));   // sigmoid for mask group
        om[obase + (k << 14)] = a;
    }
}

// ---------------- K2: deformable conv; writes aligned into d_out
// block = half-row (64 px), grid 1024; 8 chunks of 8 input channels.
// LDS: sl[72][64] samples + wl[64][76] weights = 37888 B -> 4 blocks/CU.
__global__ __launch_bounds__(256) void k2_deform(
    const float* __restrict__ f1, const float* __restrict__ mw,
    const float* __restrict__ om, float* __restrict__ aligned)
{
    extern __shared__ float lds[];
    float* sl = lds;             // [72][64]
    float* wl = lds + 72*64;     // [64][76] (ck stride padded to 76)

    int blk = blockIdx.x;        // b(2) y(7) xh(1)
    int xh = blk & 1;
    int y  = (blk >> 1) & 127;
    int b  = blk >> 8;

    int tid = threadIdx.x;
    int px  = tid & 63;          // local x within half-row
    int cs  = tid >> 6;          // 0..3 channel-slot
    int gx  = xh*64 + px;

    int oo = tid & 15;
    int pg = tid >> 4;           // 0..15

    float acc[4][4];
#pragma unroll
    for (int j = 0; j < 4; ++j)
#pragma unroll
        for (int p = 0; p < 4; ++p) acc[j][p] = 0.f;

    const float* omb = om + ((b*27) << 14) + (y << 7);
    const float* f1b = f1 + ((size_t)(b*CC) << 14);

    for (int chunk = 0; chunk < 8; ++chunk) {
        // stage weights: wl[o][ck] = mw[o*576 + chunk*72 + ck], ck in [0,72)
        for (int q = tid; q < 64*18; q += 256) {
            int o = q / 18;
            int ck4 = (q - o*18) * 4;
            float4 wv = *(const float4*)&mw[o*576 + chunk*72 + ck4];
            *(float4*)&wl[o*76 + ck4] = wv;
        }

        // phase A: bilinear sampling, 2 channels per thread
#pragma unroll
        for (int k = 0; k < 9; ++k) {
            float off0 = omb[((2*k)   << 14) + gx];
            float off1 = omb[((2*k+1) << 14) + gx];
            float mk   = omb[((18+k)  << 14) + gx];   // already sigmoided in K1

            float pyf = (float)y  + (float)(k/3) - 1.f + off0;
            float pxg = (float)gx + (float)(k%3) - 1.f + off1;
            float fy = floorf(pyf), fx = floorf(pxg);
            int y0 = (int)fy, x0 = (int)fx;
            float wy = pyf - fy, wx = pxg - fx;
            float oy = 1.f - wy, ox = 1.f - wx;
            float w00 = oy*ox, w01 = oy*wx, w10 = wy*ox, w11 = wy*wx;
            bool yv0 = (unsigned)y0     < (unsigned)HH;
            bool yv1 = (unsigned)(y0+1) < (unsigned)HH;
            bool xv0 = (unsigned)x0     < (unsigned)WW;
            bool xv1 = (unsigned)(x0+1) < (unsigned)WW;
            int i00 = y0*WW + x0;

#pragma unroll
            for (int cl = 0; cl < 2; ++cl) {
                int c_loc = cs*2 + cl;
                int c = chunk*8 + c_loc;
                const float* src = f1b + (c << 14);
                float s = 0.f;
                if (yv0 && xv0) s += w00 * src[i00];
                if (yv0 && xv1) s += w01 * src[i00 + 1];
                if (yv1 && xv0) s += w10 * src[i00 + WW];
                if (yv1 && xv1) s += w11 * src[i00 + WW + 1];
                sl[(c_loc*9 + k)*64 + px] = s * mk;
            }
        }
        __syncthreads();

        // phase B: acc[j][p] += wl[oo+16j][ck+i] * sl[ck+i][pg*4+p]
        for (int ck = 0; ck < 72; ck += 4) {
            float4 s0 = *(const float4*)&sl[(ck+0)*64 + pg*4];
            float4 s1 = *(const float4*)&sl[(ck+1)*64 + pg*4];
            float4 s2 = *(const float4*)&sl[(ck+2)*64 + pg*4];
            float4 s3 = *(const float4*)&sl[(ck+3)*64 + pg*4];
#pragma unroll
            for (int j = 0; j < 4; ++j) {
                float4 wv = *(const float4*)&wl[(oo + 16*j)*76 + ck];
                acc[j][0] += wv.x*s0.x + wv.y*s1.x + wv.z*s2.x + wv.w*s3.x;
                acc[j][1] += wv.x*s0.y + wv.y*s1.y + wv.z*s2.y + wv.w*s3.y;
                acc[j][2] += wv.x*s0.z + wv.y*s1.z + wv.z*s2.z + wv.w*s3.z;
                acc[j][3] += wv.x*s0.w + wv.y*s1.w + wv.z*s2.w + wv.w*s3.w;
            }
        }
        __syncthreads();
    }

#pragma unroll
    for (int j = 0; j < 4; ++j) {
        int o = oo + 16*j;
        float4 v = make_float4(acc[j][0], acc[j][1], acc[j][2], acc[j][3]);
        *(float4*)&aligned[((b*CC + o) << 14) + (y << 7) + xh*64 + pg*4] = v;
    }
}

// ---------------- K3: per-channel partial sum / sumsq; grid 128 = (c, batch-half)
__global__ __launch_bounds__(256) void k3_stats(
    const float* __restrict__ a, float* __restrict__ stats)
{
    int c = blockIdx.x & 63;
    int half = blockIdx.x >> 6;
    int tid = threadIdx.x;
    float s = 0.f, s2 = 0.f;
    for (int bimg = half*2; bimg < half*2 + 2; ++bimg) {
        const float* base = a + ((size_t)(bimg*CC + c) << 14);
        for (int i = tid*4; i < HWP; i += 256*4) {
            float4 v = *(const float4*)&base[i];
            s  += v.x + v.y + v.z + v.w;
            s2 += v.x*v.x + v.y*v.y + v.z*v.z + v.w*v.w;
        }
    }
    for (int off = 32; off > 0; off >>= 1) {
        s  += __shfl_down(s,  off, 64);
        s2 += __shfl_down(s2, off, 64);
    }
    __shared__ float rs[4], rs2[4];
    int w = tid >> 6;
    if ((tid & 63) == 0) { rs[w] = s; rs2[w] = s2; }
    __syncthreads();
    if (tid == 0) {
        stats[half*128 + c]      = rs[0] + rs[1] + rs[2] + rs[3];
        stats[half*128 + 64 + c] = rs2[0] + rs2[1] + rs2[2] + rs2[3];
    }
}

// ---------------- K4: in-place normalize + affine (combines the 2 partials)
__global__ __launch_bounds__(256) void k4_norm(
    float* __restrict__ a, const float* __restrict__ stats,
    const float* __restrict__ gamma, const float* __restrict__ beta)
{
    const float invN = 1.f / 65536.f;
    int n4 = (BB*CC*HWP) / 4;
    for (int i4 = blockIdx.x*256 + threadIdx.x; i4 < n4; i4 += gridDim.x*256) {
        int c = (i4 >> 12) & 63;
        float mean = (stats[c] + stats[128 + c]) * invN;
        float var  = (stats[64 + c] + stats[192 + c]) * invN - mean*mean;
        float sc = gamma[c] * rsqrtf(var + 1e-5f);
        float sh = beta[c] - mean*sc;
        float4 v = ((const float4*)a)[i4];
        v.x = v.x*sc + sh; v.y = v.y*sc + sh;
        v.z = v.z*sc + sh; v.w = v.w*sc + sh;
        ((float4*)a)[i4] = v;
    }
}

extern "C" void kernel_launch(void* const* d_in, const int* in_sizes, int n_in,
                              void* d_out, int out_size, void* d_ws, size_t ws_size,
                              hipStream_t stream)
{
    const float* f1    = (const float*)d_in[0];
    const float* f3    = (const float*)d_in[1];
    const float* ow    = (const float*)d_in[2];
    const float* ob    = (const float*)d_in[3];
    const float* mw    = (const float*)d_in[4];
    const float* gamma = (const float*)d_in[5];
    const float* beta  = (const float*)d_in[6];
    float* out = (float*)d_out;

    float* om    = (float*)d_ws;               // [4][27][128][128] = 7,077,888 B
    float* stats = om + 4*27*HWP;              // [256] floats

    const int lds1 = 9*128*10*4;               // 46,080 B -> 3 blocks/CU
    const int lds2 = (72*64 + 64*76)*4;        // 37,888 B -> 4 blocks/CU
    (void)hipFuncSetAttribute((const void*)k1_offset_conv,
        hipFuncAttributeMaxDynamicSharedMemorySize, lds1);
    (void)hipFuncSetAttribute((const void*)k2_deform,
        hipFuncAttributeMaxDynamicSharedMemorySize, lds2);

    hipLaunchKernelGGL(k1_offset_conv, dim3(256, 3), dim3(256), lds1, stream,
                       f1, f3, ow, ob, om);
    hipLaunchKernelGGL(k2_deform, dim3(1024), dim3(256), lds2, stream,
                       f1, mw, om, out);
    hipLaunchKernelGGL(k3_stats, dim3(128), dim3(256), 0, stream, out, stats);
    hipLaunchKernelGGL(k4_norm, dim3(2048), dim3(256), 0, stream,
                       out, stats, gamma, beta);
}

// Round 3
// 594.236 us; speedup vs baseline: 1.2192x; 1.0823x over previous
//
#include <hip/hip_runtime.h>
#include <math.h>

#define BB 4
#define CC 64
#define HH 128
#define WW 128
#define HWP 16384

// ---------------- K0: transpose offset-conv weights to [grp][c][k*9+t] (stride 96)
__global__ __launch_bounds__(256) void k0_wt(
    const float* __restrict__ ow, float* __restrict__ owt)
{
    int i = blockIdx.x*256 + threadIdx.x;      // over 27*128*9 = 31104
    if (i < 27*128*9) {
        int t  = i % 9;
        int r  = i / 9;
        int c  = r % 128;
        int ko = r / 128;                      // 0..26
        int grp = ko / 9, kk = ko % 9;
        owt[(grp*128 + c)*96 + kk*9 + t] = ow[i];
    }
}

// ---------------- K1: 3x3 conv over concat[f1,f3] -> om [B][27][H][W]
// No LDS. Weights read via wave-uniform indices -> SGPRs (scalar loads).
// Group 2 (channels 18..26) gets sigmoid applied (mask).
__global__ __launch_bounds__(256) void k1_offset_conv(
    const float* __restrict__ f1, const float* __restrict__ f3,
    const float* __restrict__ owt, const float* __restrict__ ob,
    float* __restrict__ om)
{
    int grp = blockIdx.y;          // 0..2
    int pix = blockIdx.x*256 + threadIdx.x;
    int b = pix >> 14;
    int y = (pix >> 7) & 127;
    int x = pix & 127;

    int   toff[9];
    float tval[9];
#pragma unroll
    for (int t = 0; t < 9; ++t) {
        int yy = y + t/3 - 1;
        int xx = x + (t % 3) - 1;
        bool ok = ((unsigned)yy < (unsigned)HH) && ((unsigned)xx < (unsigned)WW);
        tval[t] = ok ? 1.f : 0.f;
        toff[t] = ok ? (yy*WW + xx) : 0;
    }

    float acc[9];
#pragma unroll
    for (int k = 0; k < 9; ++k) acc[k] = ob[grp*9 + k];

    const float* base0 = f1 + ((size_t)(b*CC) << 14);
    const float* base1 = f3 + ((size_t)(b*CC) << 14);
    const float* wgs = owt + grp*128*96;       // uniform base

    for (int half = 0; half < 2; ++half) {
        const float* srcb = (half == 0) ? base0 : base1;
        for (int c0 = 0; c0 < 64; ++c0) {
            const float* src = srcb + (c0 << 14);
            float v[9];
#pragma unroll
            for (int t = 0; t < 9; ++t) v[t] = tval[t] * src[toff[t]];
            const float* wr = wgs + (half*64 + c0)*96;   // uniform
#pragma unroll
            for (int k = 0; k < 9; ++k)
#pragma unroll
                for (int t = 0; t < 9; ++t)
                    acc[k] = fmaf(v[t], wr[k*9 + t], acc[k]);
        }
    }

    int obase = ((b*27 + grp*9) << 14) + (y << 7) + x;
#pragma unroll
    for (int k = 0; k < 9; ++k) {
        float a = acc[k];
        if (grp == 2) a = 1.f / (1.f + __expf(-a));   // sigmoid for mask group
        om[obase + (k << 14)] = a;
    }
}

// ---------------- K2: deformable conv; writes aligned into d_out
// block = half-row (64 px), grid 1024; 8 chunks of 8 input channels.
// LDS: sl[72][64] + wl[64][76] = 37888 B -> 4 blocks/CU (16 waves) if VGPR<=128.
__global__ __launch_bounds__(256) void k2_deform(
    const float* __restrict__ f1, const float* __restrict__ mw,
    const float* __restrict__ om, float* __restrict__ aligned)
{
    extern __shared__ float lds[];
    float* sl = lds;             // [72][64]
    float* wl = lds + 72*64;     // [64][76] (ck stride padded to 76)

    int blk = blockIdx.x;        // b(2) y(7) xh(1)
    int xh = blk & 1;
    int y  = (blk >> 1) & 127;
    int b  = blk >> 8;

    int tid = threadIdx.x;
    int px  = tid & 63;          // local x within half-row
    int cs  = tid >> 6;          // 0..3 channel-slot
    int gx  = xh*64 + px;

    int oo = tid & 15;
    int pg = tid >> 4;           // 0..15

    float acc[4][4];
#pragma unroll
    for (int j = 0; j < 4; ++j)
#pragma unroll
        for (int p = 0; p < 4; ++p) acc[j][p] = 0.f;

    const float* omb = om + ((b*27) << 14) + (y << 7);
    const float* f1b = f1 + ((size_t)(b*CC) << 14);

    for (int chunk = 0; chunk < 8; ++chunk) {
        // stage weights: wl[o][ck] = mw[o*576 + chunk*72 + ck]
        for (int q = tid; q < 64*18; q += 256) {
            int o = q / 18;
            int ck4 = (q - o*18) * 4;
            float4 wv = *(const float4*)&mw[o*576 + chunk*72 + ck4];
            *(float4*)&wl[o*76 + ck4] = wv;
        }

        // phase A: bilinear sampling, 2 channels per thread (k loop NOT unrolled
        // -> keeps VGPR low; offset reloads are coalesced L1/L2 hits)
        for (int k = 0; k < 9; ++k) {
            float off0 = omb[((2*k)   << 14) + gx];
            float off1 = omb[((2*k+1) << 14) + gx];
            float mk   = omb[((18+k)  << 14) + gx];   // already sigmoided in K1

            float pyf = (float)y  + (float)(k/3) - 1.f + off0;
            float pxg = (float)gx + (float)(k%3) - 1.f + off1;
            float fy = floorf(pyf), fx = floorf(pxg);
            int y0 = (int)fy, x0 = (int)fx;
            float wy = pyf - fy, wx = pxg - fx;
            float oy = 1.f - wy, ox = 1.f - wx;
            float w00 = oy*ox, w01 = oy*wx, w10 = wy*ox, w11 = wy*wx;
            bool yv0 = (unsigned)y0     < (unsigned)HH;
            bool yv1 = (unsigned)(y0+1) < (unsigned)HH;
            bool xv0 = (unsigned)x0     < (unsigned)WW;
            bool xv1 = (unsigned)(x0+1) < (unsigned)WW;
            int i00 = y0*WW + x0;

#pragma unroll
            for (int cl = 0; cl < 2; ++cl) {
                int c_loc = cs*2 + cl;
                int c = chunk*8 + c_loc;
                const float* src = f1b + (c << 14);
                float s = 0.f;
                if (yv0 && xv0) s += w00 * src[i00];
                if (yv0 && xv1) s += w01 * src[i00 + 1];
                if (yv1 && xv0) s += w10 * src[i00 + WW];
                if (yv1 && xv1) s += w11 * src[i00 + WW + 1];
                sl[(c_loc*9 + k)*64 + px] = s * mk;
            }
        }
        __syncthreads();

        // phase B: acc[j][p] += wl[oo+16j][ck+i] * sl[ck+i][pg*4+p]
        for (int ck = 0; ck < 72; ck += 4) {
            float4 s0 = *(const float4*)&sl[(ck+0)*64 + pg*4];
            float4 s1 = *(const float4*)&sl[(ck+1)*64 + pg*4];
            float4 s2 = *(const float4*)&sl[(ck+2)*64 + pg*4];
            float4 s3 = *(const float4*)&sl[(ck+3)*64 + pg*4];
#pragma unroll
            for (int j = 0; j < 4; ++j) {
                float4 wv = *(const float4*)&wl[(oo + 16*j)*76 + ck];
                acc[j][0] += wv.x*s0.x + wv.y*s1.x + wv.z*s2.x + wv.w*s3.x;
                acc[j][1] += wv.x*s0.y + wv.y*s1.y + wv.z*s2.y + wv.w*s3.y;
                acc[j][2] += wv.x*s0.z + wv.y*s1.z + wv.z*s2.z + wv.w*s3.z;
                acc[j][3] += wv.x*s0.w + wv.y*s1.w + wv.z*s2.w + wv.w*s3.w;
            }
        }
        __syncthreads();
    }

#pragma unroll
    for (int j = 0; j < 4; ++j) {
        int o = oo + 16*j;
        float4 v = make_float4(acc[j][0], acc[j][1], acc[j][2], acc[j][3]);
        *(float4*)&aligned[((b*CC + o) << 14) + (y << 7) + xh*64 + pg*4] = v;
    }
}

// ---------------- K3: per-channel partial sum / sumsq; grid 128 = (c, batch-half)
__global__ __launch_bounds__(256) void k3_stats(
    const float* __restrict__ a, float* __restrict__ stats)
{
    int c = blockIdx.x & 63;
    int half = blockIdx.x >> 6;
    int tid = threadIdx.x;
    float s = 0.f, s2 = 0.f;
    for (int bimg = half*2; bimg < half*2 + 2; ++bimg) {
        const float* base = a + ((size_t)(bimg*CC + c) << 14);
        for (int i = tid*4; i < HWP; i += 256*4) {
            float4 v = *(const float4*)&base[i];
            s  += v.x + v.y + v.z + v.w;
            s2 += v.x*v.x + v.y*v.y + v.z*v.z + v.w*v.w;
        }
    }
    for (int off = 32; off > 0; off >>= 1) {
        s  += __shfl_down(s,  off, 64);
        s2 += __shfl_down(s2, off, 64);
    }
    __shared__ float rs[4], rs2[4];
    int w = tid >> 6;
    if ((tid & 63) == 0) { rs[w] = s; rs2[w] = s2; }
    __syncthreads();
    if (tid == 0) {
        stats[half*128 + c]      = rs[0] + rs[1] + rs[2] + rs[3];
        stats[half*128 + 64 + c] = rs2[0] + rs2[1] + rs2[2] + rs2[3];
    }
}

// ---------------- K4: in-place normalize + affine (combines the 2 partials)
__global__ __launch_bounds__(256) void k4_norm(
    float* __restrict__ a, const float* __restrict__ stats,
    const float* __restrict__ gamma, const float* __restrict__ beta)
{
    const float invN = 1.f / 65536.f;
    int n4 = (BB*CC*HWP) / 4;
    for (int i4 = blockIdx.x*256 + threadIdx.x; i4 < n4; i4 += gridDim.x*256) {
        int c = (i4 >> 12) & 63;
        float mean = (stats[c] + stats[128 + c]) * invN;
        float var  = (stats[64 + c] + stats[192 + c]) * invN - mean*mean;
        float sc = gamma[c] * rsqrtf(var + 1e-5f);
        float sh = beta[c] - mean*sc;
        float4 v = ((const float4*)a)[i4];
        v.x = v.x*sc + sh; v.y = v.y*sc + sh;
        v.z = v.z*sc + sh; v.w = v.w*sc + sh;
        ((float4*)a)[i4] = v;
    }
}

extern "C" void kernel_launch(void* const* d_in, const int* in_sizes, int n_in,
                              void* d_out, int out_size, void* d_ws, size_t ws_size,
                              hipStream_t stream)
{
    const float* f1    = (const float*)d_in[0];
    const float* f3    = (const float*)d_in[1];
    const float* ow    = (const float*)d_in[2];
    const float* ob    = (const float*)d_in[3];
    const float* mw    = (const float*)d_in[4];
    const float* gamma = (const float*)d_in[5];
    const float* beta  = (const float*)d_in[6];
    float* out = (float*)d_out;

    float* om    = (float*)d_ws;               // [4][27][128][128] = 7,077,888 B
    float* stats = om + 4*27*HWP;              // [256] floats
    float* owt   = stats + 256;                // [3][128][96] = 147,456 B

    const int lds2 = (72*64 + 64*76)*4;        // 37,888 B
    (void)hipFuncSetAttribute((const void*)k2_deform,
        hipFuncAttributeMaxDynamicSharedMemorySize, lds2);

    hipLaunchKernelGGL(k0_wt, dim3(122), dim3(256), 0, stream, ow, owt);
    hipLaunchKernelGGL(k1_offset_conv, dim3(256, 3), dim3(256), 0, stream,
                       f1, f3, owt, ob, om);
    hipLaunchKernelGGL(k2_deform, dim3(1024), dim3(256), lds2, stream,
                       f1, mw, om, out);
    hipLaunchKernelGGL(k3_stats, dim3(128), dim3(256), 0, stream, out, stats);
    hipLaunchKernelGGL(k4_norm, dim3(2048), dim3(256), 0, stream,
                       out, stats, gamma, beta);
}